// Round 1
// baseline (119.527 us; speedup 1.0000x reference)
//
#include <hip/hip_runtime.h>

// ---------------------------------------------------------------------------
// metaLinear: y[t,o] = sum_j x2[t,j] * ( x1[t,:]@W[j*64+o,:] + bvec[j*64+o] )
//   T=16384, IN1=256, IN2=64 (j), OUT=64 (o).
// Round 3: occupancy + L1-redundancy fix.
//   - grid 512 (o-half per WG) -> 2 blocks/CU -> 2 waves/SIMD (was 1)
//   - Wf staged per-j into LDS via global_load_lds (linear frag order), so
//     th-pair waves no longer stream identical frags through L1 twice
//   - bias moved out of the K-loop (16 frags/j, not 17); bias term is a tiny
//     K=64 GEMM computed by prep_bias directly into out; epilogue does +=
//   - waves = th(2) x jh(2); j-halves reduced through LDS at the end
// LDS = rings 4*16KB + sX2 16KB = 81920 B exactly -> 2 blocks/CU.
// ---------------------------------------------------------------------------

#define FRAGS 16                         // data k-steps per j (K=256)
#define FRAG_SHORTS 512                  // 64 lanes * 8 bf16
#define JF_SHORTS (FRAGS * FRAG_SHORTS)  // 8192 shorts per (j, oh) frame

typedef __bf16 bf16x8 __attribute__((ext_vector_type(8)));
typedef float  f32x16 __attribute__((ext_vector_type(16)));

static __device__ __forceinline__ unsigned short f2bf(float f) {
  union { float f; unsigned u; } v; v.f = f;
  unsigned r = v.u + 0x7FFFu + ((v.u >> 16) & 1u);   // RNE
  return (unsigned short)(r >> 16);
}

static __device__ __forceinline__ void gload_lds16(const unsigned short* g,
                                                   unsigned short* l) {
  __builtin_amdgcn_global_load_lds(
      (const __attribute__((address_space(1))) void*)g,
      (__attribute__((address_space(3))) void*)l, 16, 0, 0);
}

// Pre-shuffle W into A-fragment order (no bias frag):
//   Wf[((j*2+oh)*16 + ks)*512 + lane*8 + e] =
//       bf16( W[row = 64j+32oh+(lane&31)][col = 16ks + 8*(lane>>5) + e] )
__global__ void prep_w(const float* __restrict__ W,
                       unsigned short* __restrict__ Wf) {
  int idx = blockIdx.x * 256 + threadIdx.x;   // 65536 total
  int r  = idx >> 4;                          // W row 0..4095
  int ks = idx & 15;                          // k-step 0..15
  int j   = r >> 6;
  int o   = r & 63;
  int oh  = o >> 5;
  int l31 = o & 31;
  size_t fb = ((size_t)(j * 2 + oh) * FRAGS + ks) * FRAG_SHORTS;

  const float4* row = (const float4*)(W + (size_t)r * 256 + ks * 16);
  float4 v0 = row[0], v1 = row[1], v2 = row[2], v3 = row[3];
  ushort4 lo0, lo1, hi0, hi1;
  lo0.x = f2bf(v0.x); lo0.y = f2bf(v0.y); lo0.z = f2bf(v0.z); lo0.w = f2bf(v0.w);
  lo1.x = f2bf(v1.x); lo1.y = f2bf(v1.y); lo1.z = f2bf(v1.z); lo1.w = f2bf(v1.w);
  hi0.x = f2bf(v2.x); hi0.y = f2bf(v2.y); hi0.z = f2bf(v2.z); hi0.w = f2bf(v2.w);
  hi1.x = f2bf(v3.x); hi1.y = f2bf(v3.y); hi1.z = f2bf(v3.z); hi1.w = f2bf(v3.w);
  *(ushort4*)&Wf[fb + l31 * 8 + 0] = lo0;            // lane l31 (lg=0)
  *(ushort4*)&Wf[fb + l31 * 8 + 4] = lo1;
  *(ushort4*)&Wf[fb + 256 + l31 * 8 + 0] = hi0;      // lane 32+l31 (lg=1)
  *(ushort4*)&Wf[fb + 256 + l31 * 8 + 4] = hi1;
}

// Bias term: out[t,o] = sum_j x2[t,j] * bvec[j*64+o]  (f32, exact).
// Block = 4 tokens x 64 o. Main kernel accumulates (+=) on top.
__global__ void prep_bias(const float* __restrict__ x2,
                          const float* __restrict__ bv,
                          float* __restrict__ out) {
  __shared__ float sbv[4096];
  __shared__ float sx2[256];
  int tid = threadIdx.x;
  #pragma unroll
  for (int i = 0; i < 16; ++i) sbv[i * 256 + tid] = bv[i * 256 + tid];
  long t0 = (long)blockIdx.x * 4;
  sx2[tid] = x2[t0 * 64 + tid];
  __syncthreads();
  int o = tid & 63, tl = tid >> 6;
  float acc = 0.f;
  #pragma unroll
  for (int j = 0; j < 64; ++j) acc += sx2[tl * 64 + j] * sbv[j * 64 + o];
  out[(t0 + tl) * 64 + o] = acc;
}

// Main fused kernel. 512 WGs x 256 threads (4 waves).
// bid -> (tile, oh) XCD-aware: both oh halves of a tile on the same XCD.
// Wave wv: th = wv&1 (32-token subtile), jh = wv>>1 (j half).
__global__ __launch_bounds__(256, 2)
void meta_main(const float* __restrict__ x1, const float* __restrict__ x2,
               const unsigned short* __restrict__ Wf, float* __restrict__ out) {
  __shared__ unsigned short sWf[4 * JF_SHORTS];   // 64 KB: ring[jh][buf]
  __shared__ float sX2[64 * 64];                  // 16 KB: x2 transposed [j][t]

  const int tid  = threadIdx.x;
  const int lane = tid & 63;
  const int wv   = tid >> 6;
  const int th   = wv & 1;
  const int jh   = wv >> 1;
  const int l31  = lane & 31;
  const int lg   = lane >> 5;

  const int bid  = blockIdx.x;
  const int oh   = (bid >> 3) & 1;                       // same XCD as pair
  const int tile = (bid & 7) + ((bid >> 4) << 3);        // 0..255, bijective
  const long tile0 = (long)tile * 64;

  // ---- stage x1 tile fp32 -> bf16 (LD=264) into ring region; x2 -> sX2 ----
  {
    unsigned short* sX1 = sWf;                           // transient
    const float4* src = (const float4*)(x1 + tile0 * 256);
    #pragma unroll
    for (int it = 0; it < 16; ++it) {
      int fi4 = it * 256 + tid;
      float4 v = src[fi4];
      int token = fi4 >> 6;
      int col   = (fi4 & 63) * 4;
      ushort4 b;
      b.x = f2bf(v.x); b.y = f2bf(v.y); b.z = f2bf(v.z); b.w = f2bf(v.w);
      *(ushort4*)&sX1[token * 264 + col] = b;
    }
    const float4* s2 = (const float4*)(x2 + tile0 * 64);
    #pragma unroll
    for (int it = 0; it < 4; ++it) {
      int fi4 = it * 256 + tid;
      float4 v = s2[fi4];
      int token = fi4 >> 4;
      int j0    = (fi4 & 15) * 4;
      sX2[(j0 + 0) * 64 + token] = v.x;
      sX2[(j0 + 1) * 64 + token] = v.y;
      sX2[(j0 + 2) * 64 + token] = v.z;
      sX2[(j0 + 3) * 64 + token] = v.w;
    }
  }
  __syncthreads();

  // ---- x1 B-frags, register-resident for the whole j-loop ----
  bf16x8 bfrag[FRAGS];
  {
    const unsigned short* base = &sWf[(32 * th + l31) * 264 + lg * 8];
    #pragma unroll
    for (int ks = 0; ks < FRAGS; ++ks)
      bfrag[ks] = *(const bf16x8*)(base + ks * 16);
  }
  __syncthreads();                           // x1 reads done; rings may reuse

  const int jbase = jh * 32;
  unsigned short* ring = &sWf[jh * 2 * JF_SHORTS];
  const unsigned short* wlane =
      Wf + ((size_t)(jbase * 2 + oh)) * JF_SHORTS + lane * 8;

  // prologue: stage j-local 0 into ring buf0 (th==0 wave of each jh)
  if (th == 0) {
    #pragma unroll
    for (int ks = 0; ks < FRAGS; ++ks)
      gload_lds16(wlane + ks * FRAG_SHORTS, &ring[ks * FRAG_SHORTS]);
  }
  __syncthreads();

  f32x16 yacc;
  #pragma unroll
  for (int r = 0; r < 16; ++r) yacc[r] = 0.0f;

  const int tt = 32 * th + l31;              // this lane's token column

  #pragma unroll 2
  for (int jl = 0; jl < 32; ++jl) {
    const int buf = jl & 1;
    // stage next j into the other buffer (completes at the end barrier)
    if (th == 0 && jl + 1 < 32) {
      const unsigned short* p = wlane + (size_t)(jl + 1) * 2 * JF_SHORTS;
      unsigned short* d = &ring[(buf ^ 1) * JF_SHORTS];
      #pragma unroll
      for (int ks = 0; ks < FRAGS; ++ks)
        gload_lds16(p + ks * FRAG_SHORTS, d + ks * FRAG_SHORTS);
    }
    // compute from ring[buf]
    const unsigned short* rb = &ring[buf * JF_SHORTS] + lane * 8;
    f32x16 wlo, whi;
    #pragma unroll
    for (int r = 0; r < 16; ++r) { wlo[r] = 0.0f; whi[r] = 0.0f; }
    #pragma unroll
    for (int ks = 0; ks < 8; ++ks) {
      bf16x8 wk = *(const bf16x8*)(rb + ks * FRAG_SHORTS);
      wlo = __builtin_amdgcn_mfma_f32_32x32x16_bf16(wk, bfrag[ks], wlo, 0, 0, 0);
    }
    #pragma unroll
    for (int ks = 8; ks < 16; ++ks) {
      bf16x8 wk = *(const bf16x8*)(rb + ks * FRAG_SHORTS);
      whi = __builtin_amdgcn_mfma_f32_32x32x16_bf16(wk, bfrag[ks], whi, 0, 0, 0);
    }
    float x2s = sX2[(jbase + jl) * 64 + tt];
    #pragma unroll
    for (int r = 0; r < 16; ++r) yacc[r] += x2s * (wlo[r] + whi[r]);
    __syncthreads();
  }

  // ---- jh reduction through LDS (ring space is free now), then += out ----
  float* red = (float*)sWf;                  // 2*64*17 f32 = 8704 B, padded
  if (jh == 1) {
    #pragma unroll
    for (int r = 0; r < 16; ++r) red[(th * 64 + lane) * 17 + r] = yacc[r];
  }
  __syncthreads();
  if (jh == 0) {
    const float* rd = &red[(th * 64 + lane) * 17];
    float* yout = out + (tile0 + tt) * 64 + oh * 32;
    #pragma unroll
    for (int r = 0; r < 16; ++r) {
      int ol = (r & 3) + 8 * (r >> 2) + 4 * lg;
      yout[ol] += yacc[r] + rd[r];           // bias term already in out
    }
  }
}

extern "C" void kernel_launch(void* const* d_in, const int* in_sizes, int n_in,
                              void* d_out, int out_size, void* d_ws, size_t ws_size,
                              hipStream_t stream) {
  const float* x1 = (const float*)d_in[0];   // (4,4096,256) f32
  const float* x2 = (const float*)d_in[1];   // (4,4096,64)  f32
  const float* W  = (const float*)d_in[2];   // (4096,256)   f32
  const float* bv = (const float*)d_in[3];   // (4096,)      f32
  float* y = (float*)d_out;                  // (4,4096,64)  f32
  unsigned short* Wf = (unsigned short*)d_ws;  // 64*2*8192*2 = 2,097,152 B

  prep_w<<<256, 256, 0, stream>>>(W, Wf);
  prep_bias<<<4096, 256, 0, stream>>>(x2, bv, y);
  meta_main<<<512, 256, 0, stream>>>(x1, x2, Wf, y);
}

// Round 2
// 105.556 us; speedup vs baseline: 1.1324x; 1.1324x over previous
//
#include <hip/hip_runtime.h>

// ---------------------------------------------------------------------------
// metaLinear: y[t,o] = sum_j x2[t,j] * ( x1[t,:]@W[j*64+o,:] + bvec[j*64+o] )
//   T=16384, IN1=256, IN2=64 (j), OUT=64 (o).
// Round 4: LDS-bandwidth fix via 2-tile (64-token) waves + bias-as-MFMA-init.
//   - BM=128 tokens, 256 blocks (128 tiles x 2 oh), 512 thr = 8 waves
//     = th(2: 64-token halves) x jh(4: 16-j quarters)
//   - each W fragment read from LDS once -> feeds 2 MFMAs (tile A, tile B):
//     per-CU LDS read traffic halves vs round 3
//   - prep_bias kernel REMOVED: bias = one extra MFMA per tile initializing
//     yacc (A = bvec fragments, B = bf16(x2) fragment); epilogue pure store
//   - LDS: ring 4 streams x 2 bufs x 16KB = 128KB + sX2 32KB = 160KB exact
// ---------------------------------------------------------------------------

#define FRAGS 16                         // data k-steps per j (K=256)
#define FRAG_SHORTS 512                  // 64 lanes * 8 bf16
#define JF_SHORTS (FRAGS * FRAG_SHORTS)  // 8192 shorts = 16 KB per (j, oh)
#define BIAS_OFF ((size_t)(64 * 2 * FRAGS) * FRAG_SHORTS)   // 1048576 shorts

typedef __bf16 bf16x8 __attribute__((ext_vector_type(8)));
typedef float  f32x16 __attribute__((ext_vector_type(16)));

static __device__ __forceinline__ unsigned short f2bf(float f) {
  union { float f; unsigned u; } v; v.f = f;
  unsigned r = v.u + 0x7FFFu + ((v.u >> 16) & 1u);   // RNE
  return (unsigned short)(r >> 16);
}

static __device__ __forceinline__ void gload_lds16(const unsigned short* g,
                                                   unsigned short* l) {
  __builtin_amdgcn_global_load_lds(
      (const __attribute__((address_space(1))) void*)g,
      (__attribute__((address_space(3))) void*)l, 16, 0, 0);
}

// Pre-shuffle W into A-fragment order (16 frags per (j,oh)):
//   Wf[((j*2+oh)*16 + ks)*512 + lane*8 + e] =
//       bf16( W[row = 64j+32oh+(lane&31)][col = 16ks + 8*(lane>>5) + e] )
// plus 8 bias A-frames at BIAS_OFF, frame f = oh*4+jh:
//   Bf[f*512 + lane*8 + e] = bf16( bvec[(jh*16 + 8*(lane>>5)+e)*64 + 32oh + (lane&31)] )
__global__ void prep_w(const float* __restrict__ W, const float* __restrict__ bv,
                       unsigned short* __restrict__ Wf) {
  int idx = blockIdx.x * 256 + threadIdx.x;   // 65536 total
  int r  = idx >> 4;                          // W row 0..4095
  int ks = idx & 15;                          // k-step 0..15
  int j   = r >> 6;
  int o   = r & 63;
  int oh  = o >> 5;
  int l31 = o & 31;
  size_t fb = ((size_t)(j * 2 + oh) * FRAGS + ks) * FRAG_SHORTS;

  const float4* row = (const float4*)(W + (size_t)r * 256 + ks * 16);
  float4 v0 = row[0], v1 = row[1], v2 = row[2], v3 = row[3];
  ushort4 lo0, lo1, hi0, hi1;
  lo0.x = f2bf(v0.x); lo0.y = f2bf(v0.y); lo0.z = f2bf(v0.z); lo0.w = f2bf(v0.w);
  lo1.x = f2bf(v1.x); lo1.y = f2bf(v1.y); lo1.z = f2bf(v1.z); lo1.w = f2bf(v1.w);
  hi0.x = f2bf(v2.x); hi0.y = f2bf(v2.y); hi0.z = f2bf(v2.z); hi0.w = f2bf(v2.w);
  hi1.x = f2bf(v3.x); hi1.y = f2bf(v3.y); hi1.z = f2bf(v3.z); hi1.w = f2bf(v3.w);
  *(ushort4*)&Wf[fb + l31 * 8 + 0] = lo0;            // lane l31 (lg=0)
  *(ushort4*)&Wf[fb + l31 * 8 + 4] = lo1;
  *(ushort4*)&Wf[fb + 256 + l31 * 8 + 0] = hi0;      // lane 32+l31 (lg=1)
  *(ushort4*)&Wf[fb + 256 + l31 * 8 + 4] = hi1;

  if (idx < 512) {                                   // bias A-frames
    int f   = idx >> 6;                              // 0..7 = oh*4+jh
    int ln  = idx & 63;
    int ohb = f >> 2, jhb = f & 3;
    int lb  = ln & 31, lgb = ln >> 5;
    #pragma unroll
    for (int e = 0; e < 8; ++e)
      Wf[BIAS_OFF + (size_t)f * FRAG_SHORTS + ln * 8 + e] =
          f2bf(bv[(jhb * 16 + 8 * lgb + e) * 64 + 32 * ohb + lb]);
  }
}

// Main fused kernel. 256 WGs x 512 threads (8 waves).
// bid -> (tile, oh): oh-pair of a tile on the same XCD (share x1/Wf in L2).
// Wave wv: th = wv&1 (64-token half, 2 MFMA tiles), jh = wv>>1 (j quarter).
__global__ __launch_bounds__(512, 2)
void meta_main(const float* __restrict__ x1, const float* __restrict__ x2,
               const unsigned short* __restrict__ Wf, float* __restrict__ out) {
  __shared__ __align__(16) unsigned char smem[163840];
  unsigned short* sWf = (unsigned short*)smem;      // 128 KB: x1-transient / ring / red
  float* sX2 = (float*)(smem + 131072);             // 32 KB: x2 transposed [j][t]

  const int tid  = threadIdx.x;
  const int lane = tid & 63;
  const int wv   = tid >> 6;
  const int th   = wv & 1;
  const int jh   = wv >> 1;
  const int l31  = lane & 31;
  const int lg   = lane >> 5;

  const int bid  = blockIdx.x;
  const int xcd  = bid & 7;
  const int kk   = bid >> 3;
  const int tile = xcd * 16 + (kk >> 1);            // 0..127, bijective
  const int oh   = kk & 1;
  const long tile0 = (long)tile * 128;

  // ---- stage x1 tile fp32 -> bf16 (LD=264) into transient; x2 -> sX2 ----
  {
    const float4* src = (const float4*)(x1 + tile0 * 256);
    #pragma unroll
    for (int it = 0; it < 16; ++it) {
      int fi4 = it * 512 + tid;
      float4 v = src[fi4];
      int token = fi4 >> 6;                         // 0..127
      int col   = (fi4 & 63) * 4;
      ushort4 b;
      b.x = f2bf(v.x); b.y = f2bf(v.y); b.z = f2bf(v.z); b.w = f2bf(v.w);
      *(ushort4*)&sWf[token * 264 + col] = b;
    }
    const float4* s2 = (const float4*)(x2 + tile0 * 64);
    #pragma unroll
    for (int it = 0; it < 4; ++it) {
      int fi4 = it * 512 + tid;
      float4 v = s2[fi4];
      int token = fi4 >> 4;                         // 0..127
      int j0    = (fi4 & 15) * 4;
      sX2[(j0 + 0) * 128 + token] = v.x;
      sX2[(j0 + 1) * 128 + token] = v.y;
      sX2[(j0 + 2) * 128 + token] = v.z;
      sX2[(j0 + 3) * 128 + token] = v.w;
    }
  }
  __syncthreads();

  const int tA = th * 64 + l31;                     // tile-A token (local)
  const int tB = tA + 32;                           // tile-B token (local)

  // ---- x1 B-frags, register-resident: 2 tiles x 16 frags ----
  bf16x8 bfA[16], bfB[16];
  #pragma unroll
  for (int ks = 0; ks < 16; ++ks) {
    bfA[ks] = *(const bf16x8*)&sWf[tA * 264 + ks * 16 + lg * 8];
    bfB[ks] = *(const bf16x8*)&sWf[tB * 264 + ks * 16 + lg * 8];
  }

  // ---- bias: init yacc with one MFMA per tile over this wave's 16 j ----
  f32x16 yA, yB;
  {
    union { bf16x8 v; unsigned short u[8]; } xfA, xfB;
    #pragma unroll
    for (int e = 0; e < 8; ++e) {
      int jrow = jh * 16 + 8 * lg + e;
      xfA.u[e] = f2bf(sX2[jrow * 128 + tA]);
      xfB.u[e] = f2bf(sX2[jrow * 128 + tB]);
    }
    bf16x8 biasA = *(const bf16x8*)(Wf + BIAS_OFF +
                                    (size_t)(oh * 4 + jh) * FRAG_SHORTS + lane * 8);
    f32x16 z;
    #pragma unroll
    for (int r2 = 0; r2 < 16; ++r2) z[r2] = 0.0f;
    yA = __builtin_amdgcn_mfma_f32_32x32x16_bf16(biasA, xfA.v, z, 0, 0, 0);
    yB = __builtin_amdgcn_mfma_f32_32x32x16_bf16(biasA, xfB.v, z, 0, 0, 0);
  }
  __syncthreads();                                  // transient reads done

  unsigned short* ring = sWf + jh * (2 * JF_SHORTS);
  const int ks0 = th * 8;                           // this wave stages 8 frags

  // prologue: stage j = jh*16 into buf 0
  {
    const unsigned short* src =
        Wf + ((size_t)((jh * 16) * 2 + oh) * FRAGS + ks0) * FRAG_SHORTS + lane * 8;
    unsigned short* dst = ring + ks0 * FRAG_SHORTS;
    #pragma unroll
    for (int q = 0; q < 8; ++q)
      gload_lds16(src + q * FRAG_SHORTS, dst + q * FRAG_SHORTS);
  }
  __syncthreads();

  #pragma unroll 2
  for (int i = 0; i < 16; ++i) {
    const int buf = i & 1;
    if (i + 1 < 16) {                               // prefetch next j
      const int jn = jh * 16 + i + 1;
      const unsigned short* src =
          Wf + ((size_t)(jn * 2 + oh) * FRAGS + ks0) * FRAG_SHORTS + lane * 8;
      unsigned short* dst = ring + (buf ^ 1) * JF_SHORTS + ks0 * FRAG_SHORTS;
      #pragma unroll
      for (int q = 0; q < 8; ++q)
        gload_lds16(src + q * FRAG_SHORTS, dst + q * FRAG_SHORTS);
    }
    const unsigned short* rb = ring + buf * JF_SHORTS + lane * 8;
    f32x16 aA, aB;
    #pragma unroll
    for (int r2 = 0; r2 < 16; ++r2) { aA[r2] = 0.0f; aB[r2] = 0.0f; }
    #pragma unroll
    for (int ks = 0; ks < 16; ++ks) {
      bf16x8 wk = *(const bf16x8*)(rb + ks * FRAG_SHORTS);
      aA = __builtin_amdgcn_mfma_f32_32x32x16_bf16(wk, bfA[ks], aA, 0, 0, 0);
      aB = __builtin_amdgcn_mfma_f32_32x32x16_bf16(wk, bfB[ks], aB, 0, 0, 0);
    }
    const int j = jh * 16 + i;
    const float xA = sX2[j * 128 + tA];
    const float xB = sX2[j * 128 + tB];
    #pragma unroll
    for (int r2 = 0; r2 < 16; ++r2) {
      yA[r2] += xA * aA[r2];
      yB[r2] += xB * aB[r2];
    }
    __syncthreads();
  }

  // ---- reduction over 4 jh quarters through LDS (ring space free) ----
  float* red = (float*)sWf;                         // 256 slots x 4 jh x 17 f32
  const int sA = ((th * 2 + 0) * 64 + lane) * 4 + jh;
  const int sB = ((th * 2 + 1) * 64 + lane) * 4 + jh;
  if (jh != 0) {
    #pragma unroll
    for (int r2 = 0; r2 < 16; ++r2) {
      red[sA * 17 + r2] = yA[r2];
      red[sB * 17 + r2] = yB[r2];
    }
  }
  __syncthreads();
  if (jh == 0) {
    #pragma unroll
    for (int r2 = 0; r2 < 16; ++r2) {
      yA[r2] += red[(sA + 1) * 17 + r2] + red[(sA + 2) * 17 + r2] + red[(sA + 3) * 17 + r2];
      yB[r2] += red[(sB + 1) * 17 + r2] + red[(sB + 2) * 17 + r2] + red[(sB + 3) * 17 + r2];
    }
    // D layout: col = t = l31, row(o_local) = (r&3) + 8*(r>>2) + 4*lg
    float* yoA = out + (tile0 + tA) * 64 + oh * 32;
    float* yoB = out + (tile0 + tB) * 64 + oh * 32;
    #pragma unroll
    for (int rq = 0; rq < 4; ++rq) {
      float4 vA = make_float4(yA[4 * rq + 0], yA[4 * rq + 1], yA[4 * rq + 2], yA[4 * rq + 3]);
      float4 vB = make_float4(yB[4 * rq + 0], yB[4 * rq + 1], yB[4 * rq + 2], yB[4 * rq + 3]);
      *(float4*)(yoA + 8 * rq + 4 * lg) = vA;
      *(float4*)(yoB + 8 * rq + 4 * lg) = vB;
    }
  }
}

extern "C" void kernel_launch(void* const* d_in, const int* in_sizes, int n_in,
                              void* d_out, int out_size, void* d_ws, size_t ws_size,
                              hipStream_t stream) {
  const float* x1 = (const float*)d_in[0];   // (4,4096,256) f32
  const float* x2 = (const float*)d_in[1];   // (4,4096,64)  f32
  const float* W  = (const float*)d_in[2];   // (4096,256)   f32
  const float* bv = (const float*)d_in[3];   // (4096,)      f32
  float* y = (float*)d_out;                  // (4,4096,64)  f32
  unsigned short* Wf = (unsigned short*)d_ws;  // 2 MB frags + 8 KB bias frames

  prep_w<<<256, 256, 0, stream>>>(W, bv, Wf);
  meta_main<<<256, 512, 0, stream>>>(x1, x2, Wf, y);
}